// Round 2
// baseline (5502.877 us; speedup 1.0000x reference)
//
#include <hip/hip_runtime.h>
#include <math.h>

// ---------------------------------------------------------------------------
// WeaklySupervisedDetection — f32-bit-exact RPN ordering emulation
//   conv2x2: per-tap sequential f32 FMA chains (BLAS-style), taps summed
//            ((t00+t01)+t10)+t11 + b, relu, stored f32
//   obj: f32 FMA chain + bias -> f32 logit -> correctly-rounded f32 sigmoid
//   top-K comparator: (sigmoid_f32 desc, index asc)  == lax.top_k on f32
//   reg logits: same f32 chains; box transform fp64
//   ROI-align fp64 weights -> fc6/fc7 fp32 SGEMM -> fc8 fp64 -> softmaxes fp64
// ---------------------------------------------------------------------------

#define HN 50
#define WN 50
#define CN 512
#define AN 9
#define KTOP 2048
#define NCL 20
#define NOBJ 22500  // H*W*A

// ---------------- conv 2x2 SAME, exact f32 tap chains ----------------------
// block: 256 threads = 256 consecutive cout; handles 4 consecutive hw.
__launch_bounds__(256)
__global__ void conv_chain_kernel(const float* __restrict__ feat,
                                  const float* __restrict__ rpnw,
                                  const float* __restrict__ rpnb,
                                  float* __restrict__ x32)
{
    __shared__ float xs[16 * 512];  // [hwLocal(4)][tap(4)][cin(512)]
    const int tid = threadIdx.x;
    const int hwBase = blockIdx.x * 4;
    const int co = blockIdx.y * 256 + tid;

    for (int t = tid; t < 16 * 512; t += 256) {
        int slot = t >> 9, c = t & 511;
        int hwL = slot >> 2, tap = slot & 3;
        int hw = hwBase + hwL;
        int h = hw / WN, w = hw % WN;
        int hy = h + (tap >> 1), wx = w + (tap & 1);
        float v = 0.f;
        if (hy < HN && wx < WN) v = feat[(size_t)(hy * WN + wx) * CN + c];
        xs[t] = v;
    }
    __syncthreads();

    float acc[4][4];
#pragma unroll
    for (int i = 0; i < 4; i++)
#pragma unroll
        for (int t = 0; t < 4; t++) acc[i][t] = 0.f;

    for (int c = 0; c < CN; c++) {
        float wv0 = rpnw[(size_t)(0 * CN + c) * CN + co];
        float wv1 = rpnw[(size_t)(1 * CN + c) * CN + co];
        float wv2 = rpnw[(size_t)(2 * CN + c) * CN + co];
        float wv3 = rpnw[(size_t)(3 * CN + c) * CN + co];
#pragma unroll
        for (int i = 0; i < 4; i++) {
            acc[i][0] = fmaf(xs[(i * 4 + 0) * 512 + c], wv0, acc[i][0]);
            acc[i][1] = fmaf(xs[(i * 4 + 1) * 512 + c], wv1, acc[i][1]);
            acc[i][2] = fmaf(xs[(i * 4 + 2) * 512 + c], wv2, acc[i][2]);
            acc[i][3] = fmaf(xs[(i * 4 + 3) * 512 + c], wv3, acc[i][3]);
        }
    }
    float b = rpnb[co];
#pragma unroll
    for (int i = 0; i < 4; i++) {
        float v = ((acc[i][0] + acc[i][1]) + acc[i][2]) + acc[i][3];
        v = v + b;
        v = v > 0.f ? v : 0.f;  // np.maximum order-exact
        x32[(size_t)(hwBase + i) * CN + co] = v;
    }
}

// ---------------- objectness: f32 chain -> f32 sigmoid key ------------------
__launch_bounds__(256)
__global__ void obj_chain_kernel(const float* __restrict__ x32,
                                 const float* __restrict__ clsw,
                                 const float* __restrict__ clsb,
                                 float* __restrict__ key)
{
    int i = blockIdx.x * 256 + threadIdx.x;
    if (i >= NOBJ) return;
    int hw = i / AN, a = i % AN;
    const float* xr = x32 + (size_t)hw * CN;
    float acc = 0.f;
    for (int c = 0; c < CN; c++) acc = fmaf(xr[c], clsw[c * AN + a], acc);
    float l32 = acc + clsb[a];
    // correctly-rounded f32 sigmoid of the f32 logit
    float s32 = (float)(1.0 / (1.0 + exp(-(double)l32)));
    key[i] = s32;
}

// ---------------- exact top-K rank count on (f32 key desc, idx asc) --------
__launch_bounds__(256)
__global__ void topk_count_kernel(const float* __restrict__ key, int* __restrict__ cnt)
{
    __shared__ float ch[2048];
    int tid = threadIdx.x;
    int j0 = blockIdx.y * 2048;
    for (int t = tid; t < 2048; t += 256) {
        int jg = j0 + t;
        ch[t] = (jg < NOBJ) ? key[jg] : -1.0f;
    }
    int i = blockIdx.x * 256 + tid;
    float vi = (i < NOBJ) ? key[i] : 2.0f;
    __syncthreads();
    int c = 0;
    for (int t = 0; t < 2048; t++) {
        float vj = ch[t];
        int jg = j0 + t;
        c += (vj > vi || (vj == vi && jg < i)) ? 1 : 0;
    }
    if (i < NOBJ && c) atomicAdd(&cnt[i], c);
}

__launch_bounds__(256)
__global__ void topk_scatter_kernel(const int* __restrict__ cnt, int* __restrict__ sorted)
{
    int i = blockIdx.x * 256 + threadIdx.x;
    if (i < NOBJ) {
        int r = cnt[i];
        if (r < KTOP) sorted[r] = i;
    }
}

// ---------------- box regression (f32 chains) + transform (fp64) -----------
__launch_bounds__(256)
__global__ void boxes_kernel(const int* __restrict__ sorted,
                             const float* __restrict__ x32,
                             const float* __restrict__ regw,
                             const float* __restrict__ regb,
                             double* __restrict__ boxd,
                             float* __restrict__ outBoxes)
{
    int k = blockIdx.x * 256 + threadIdx.x;
    if (k >= KTOP) return;
    int i = sorted[k];
    int hw = i / AN, a = i % AN;
    const float* xr = x32 + (size_t)hw * CN;
    float r0 = 0.f, r1 = 0.f, r2 = 0.f, r3 = 0.f;
    for (int c = 0; c < CN; c++) {
        float xv = xr[c];
        const float* wr = regw + (size_t)c * (4 * AN) + 4 * a;
        r0 = fmaf(xv, wr[0], r0);
        r1 = fmaf(xv, wr[1], r1);
        r2 = fmaf(xv, wr[2], r2);
        r3 = fmaf(xv, wr[3], r3);
    }
    r0 = r0 + regb[4 * a + 0];
    r1 = r1 + regb[4 * a + 1];
    r2 = r2 + regb[4 * a + 2];
    r3 = r3 + regb[4 * a + 3];
    double s0 = 1.0 / (1.0 + exp(-(double)r0));
    double s1 = 1.0 / (1.0 + exp(-(double)r1));
    double s2 = 1.0 / (1.0 + exp(-(double)r2));
    double s3 = 1.0 / (1.0 + exp(-(double)r3));
    double x1 = s0 * (double)(WN - 2);
    double x2 = x1 + 1.0 + s1 * ((double)(WN - 1) - x1);
    double y1 = s2 * (double)(HN - 2);
    double y2 = y1 + 1.0 + s3 * ((double)(HN - 1) - y1);
    boxd[4 * k + 0] = x1; boxd[4 * k + 1] = x2;
    boxd[4 * k + 2] = y1; boxd[4 * k + 3] = y2;
    outBoxes[4 * k + 0] = (float)x1; outBoxes[4 * k + 1] = (float)x2;
    outBoxes[4 * k + 2] = (float)y1; outBoxes[4 * k + 3] = (float)y2;
}

// ---------------- ROI align -> pooled [K, 3,3,512] (float) -----------------
__launch_bounds__(256)
__global__ void roi_kernel(const float* __restrict__ feat,
                           const double* __restrict__ boxd,
                           float* __restrict__ pooled)
{
    int k = blockIdx.x;
    int tid = threadIdx.x;
    double x1 = boxd[4 * k + 0], x2 = boxd[4 * k + 1];
    double y1 = boxd[4 * k + 2], y2 = boxd[4 * k + 3];
    int ix0[3], ix1[3], iy0[3], iy1[3];
    double fx[3], fy[3];
#pragma unroll
    for (int p = 0; p < 3; p++) {
        double t = ((double)p + 0.5) / 3.0;
        double xsv = x1 + (x2 - x1) * t;
        double x0f = floor(xsv);
        fx[p] = xsv - x0f;
        int xi = (int)x0f;
        xi = xi < 0 ? 0 : (xi > WN - 1 ? WN - 1 : xi);
        ix0[p] = xi;
        ix1[p] = (xi + 1 > WN - 1) ? WN - 1 : xi + 1;
        double ysv = y1 + (y2 - y1) * t;
        double y0f = floor(ysv);
        fy[p] = ysv - y0f;
        int yi = (int)y0f;
        yi = yi < 0 ? 0 : (yi > HN - 1 ? HN - 1 : yi);
        iy0[p] = yi;
        iy1[p] = (yi + 1 > HN - 1) ? HN - 1 : yi + 1;
    }
#pragma unroll
    for (int pp = 0; pp < 9; pp++) {
        int py = pp / 3, px = pp % 3;
        double w00 = (1.0 - fy[py]) * (1.0 - fx[px]);
        double w01 = (1.0 - fy[py]) * fx[px];
        double w10 = fy[py] * (1.0 - fx[px]);
        double w11 = fy[py] * fx[px];
        const float* f00 = feat + (size_t)(iy0[py] * WN + ix0[px]) * CN;
        const float* f01 = feat + (size_t)(iy0[py] * WN + ix1[px]) * CN;
        const float* f10 = feat + (size_t)(iy1[py] * WN + ix0[px]) * CN;
        const float* f11 = feat + (size_t)(iy1[py] * WN + ix1[px]) * CN;
        float* dst = pooled + ((size_t)k * 9 + pp) * CN;
        for (int c = tid; c < CN; c += 256) {
            double v = w00 * (double)f00[c] + w01 * (double)f01[c]
                     + w10 * (double)f10[c] + w11 * (double)f11[c];
            dst[c] = (float)v;
        }
    }
}

// ---------------- fp32 SGEMM 128x128x16, 8x8 micro-tile, bias(+relu) -------
template <bool RELU>
__launch_bounds__(256)
__global__ void sgemm128_kernel(const float* __restrict__ A,
                                const float* __restrict__ B,
                                const float* __restrict__ bias,
                                float* __restrict__ C,
                                int M, int N, int K)
{
    __shared__ float As[16][132];
    __shared__ float Bs[16][132];
    const int tid = threadIdx.x;
    const int tc = tid & 15, tr = tid >> 4;
    const int mBase = blockIdx.y * 128, nBase = blockIdx.x * 128;

    float acc[8][8];
#pragma unroll
    for (int i = 0; i < 8; i++)
#pragma unroll
        for (int j = 0; j < 8; j++) acc[i][j] = 0.f;

    const int ar = tid >> 2;
    const int ac = (tid & 3) * 4;
    const int br = tid >> 5;
    const int bc = (tid & 31) * 4;

    for (int kb = 0; kb < K; kb += 16) {
        float4 a0 = *(const float4*)&A[(size_t)(mBase + ar) * K + kb + ac];
        float4 a1 = *(const float4*)&A[(size_t)(mBase + ar + 64) * K + kb + ac];
        float4 b0 = *(const float4*)&B[(size_t)(kb + br) * N + nBase + bc];
        float4 b1 = *(const float4*)&B[(size_t)(kb + br + 8) * N + nBase + bc];
        __syncthreads();
        As[ac + 0][ar] = a0.x; As[ac + 1][ar] = a0.y;
        As[ac + 2][ar] = a0.z; As[ac + 3][ar] = a0.w;
        As[ac + 0][ar + 64] = a1.x; As[ac + 1][ar + 64] = a1.y;
        As[ac + 2][ar + 64] = a1.z; As[ac + 3][ar + 64] = a1.w;
        *(float4*)&Bs[br][bc] = b0;
        *(float4*)&Bs[br + 8][bc] = b1;
        __syncthreads();
#pragma unroll
        for (int k = 0; k < 16; k++) {
            float4 av0 = *(const float4*)&As[k][tr * 8];
            float4 av1 = *(const float4*)&As[k][tr * 8 + 4];
            float4 bv0 = *(const float4*)&Bs[k][tc * 8];
            float4 bv1 = *(const float4*)&Bs[k][tc * 8 + 4];
            float a[8] = {av0.x, av0.y, av0.z, av0.w, av1.x, av1.y, av1.z, av1.w};
            float b[8] = {bv0.x, bv0.y, bv0.z, bv0.w, bv1.x, bv1.y, bv1.z, bv1.w};
#pragma unroll
            for (int i = 0; i < 8; i++)
#pragma unroll
                for (int j = 0; j < 8; j++) acc[i][j] += a[i] * b[j];
        }
    }
#pragma unroll
    for (int i = 0; i < 8; i++) {
        size_t row = (size_t)(mBase + tr * 8 + i);
        float o[8];
#pragma unroll
        for (int j = 0; j < 8; j++) {
            float v = acc[i][j] + bias[nBase + tc * 8 + j];
            if (RELU) v = v > 0.f ? v : 0.f;
            o[j] = v;
        }
        float4 o0 = {o[0], o[1], o[2], o[3]};
        float4 o1 = {o[4], o[5], o[6], o[7]};
        *(float4*)&C[row * N + nBase + tc * 8] = o0;
        *(float4*)&C[row * N + nBase + tc * 8 + 4] = o1;
    }
}

// ---------------- fc8 (both streams), fp64 accumulate -----------------------
__launch_bounds__(256)
__global__ void fc8_kernel(const float* __restrict__ h7,
                           const float* __restrict__ cw, const float* __restrict__ cb,
                           const float* __restrict__ dw, const float* __restrict__ db,
                           double* __restrict__ lc, double* __restrict__ ld)
{
    __shared__ float hrow[4096];
    __shared__ double red[8];
    int i = blockIdx.x;
    int tid = threadIdx.x;
    for (int j = tid; j < 4096; j += 256) hrow[j] = h7[(size_t)i * 4096 + j];
    __syncthreads();
    for (int o = 0; o < NCL; o++) {
        double sc = 0.0, sd = 0.0;
        for (int j = tid; j < 4096; j += 256) {
            double hv = (double)hrow[j];
            sc += hv * (double)cw[(size_t)j * NCL + o];
            sd += hv * (double)dw[(size_t)j * NCL + o];
        }
        for (int off = 32; off > 0; off >>= 1) {
            sc += __shfl_down(sc, off, 64);
            sd += __shfl_down(sd, off, 64);
        }
        int wid = tid >> 6, lane = tid & 63;
        if (lane == 0) { red[wid] = sc; red[4 + wid] = sd; }
        __syncthreads();
        if (tid == 0) {
            lc[(size_t)i * NCL + o] = red[0] + red[1] + red[2] + red[3] + (double)cb[o];
            ld[(size_t)i * NCL + o] = red[4] + red[5] + red[6] + red[7] + (double)db[o];
        }
        __syncthreads();
    }
}

// ---------------- softmax column stats (axis=0 over 2048 regions) ----------
__launch_bounds__(256)
__global__ void colstats_kernel(const double* __restrict__ lc,
                                double* __restrict__ cmax, double* __restrict__ csum)
{
    __shared__ double red[4];
    int j = blockIdx.x, tid = threadIdx.x;
    double m = -1.0e300;
    for (int i = tid; i < KTOP; i += 256) m = fmax(m, lc[(size_t)i * NCL + j]);
    for (int off = 32; off > 0; off >>= 1) m = fmax(m, __shfl_down(m, off, 64));
    if ((tid & 63) == 0) red[tid >> 6] = m;
    __syncthreads();
    double mm = fmax(fmax(red[0], red[1]), fmax(red[2], red[3]));
    __syncthreads();
    double s = 0.0;
    for (int i = tid; i < KTOP; i += 256) s += exp(lc[(size_t)i * NCL + j] - mm);
    for (int off = 32; off > 0; off >>= 1) s += __shfl_down(s, off, 64);
    if ((tid & 63) == 0) red[tid >> 6] = s;
    __syncthreads();
    if (tid == 0) { cmax[j] = mm; csum[j] = red[0] + red[1] + red[2] + red[3]; }
}

// ---------------- row softmax + scores ---------------------------------------
__launch_bounds__(256)
__global__ void scores_kernel(const double* __restrict__ lc, const double* __restrict__ ld,
                              const double* __restrict__ cmax, const double* __restrict__ csum,
                              double* __restrict__ scd, float* __restrict__ outScores)
{
    int i = blockIdx.x * 256 + threadIdx.x;
    if (i >= KTOP) return;
    const double* lr = ld + (size_t)i * NCL;
    double rm = -1.0e300;
#pragma unroll
    for (int j = 0; j < NCL; j++) rm = fmax(rm, lr[j]);
    double rs = 0.0;
#pragma unroll
    for (int j = 0; j < NCL; j++) rs += exp(lr[j] - rm);
#pragma unroll
    for (int j = 0; j < NCL; j++) {
        double cc = exp(lc[(size_t)i * NCL + j] - cmax[j]) / csum[j];
        double dd = exp(lr[j] - rm) / rs;
        double sc = cc * dd;
        scd[(size_t)i * NCL + j] = sc;
        outScores[(size_t)i * NCL + j] = (float)sc;
    }
}

// ---------------- column sum + clip -----------------------------------------
__launch_bounds__(256)
__global__ void colsum_kernel(const double* __restrict__ scd, float* __restrict__ out)
{
    __shared__ double red[4];
    int j = blockIdx.x, tid = threadIdx.x;
    double s = 0.0;
    for (int i = tid; i < KTOP; i += 256) s += scd[(size_t)i * NCL + j];
    for (int off = 32; off > 0; off >>= 1) s += __shfl_down(s, off, 64);
    if ((tid & 63) == 0) red[tid >> 6] = s;
    __syncthreads();
    if (tid == 0) {
        double t = red[0] + red[1] + red[2] + red[3];
        t = t < 0.0 ? 0.0 : (t > 1.0 ? 1.0 : t);
        out[j] = (float)t;
    }
}

// ---------------------------------------------------------------------------
extern "C" void kernel_launch(void* const* d_in, const int* in_sizes, int n_in,
                              void* d_out, int out_size, void* d_ws, size_t ws_size,
                              hipStream_t stream)
{
    const float* features = (const float*)d_in[0];
    const float* rpn_w  = (const float*)d_in[2];
    const float* rpn_b  = (const float*)d_in[3];
    const float* cls_w  = (const float*)d_in[4];
    const float* cls_b  = (const float*)d_in[5];
    const float* reg_w  = (const float*)d_in[6];
    const float* reg_b  = (const float*)d_in[7];
    const float* fc6_w  = (const float*)d_in[8];
    const float* fc6_b  = (const float*)d_in[9];
    const float* fc7_w  = (const float*)d_in[10];
    const float* fc7_b  = (const float*)d_in[11];
    const float* fc8c_w = (const float*)d_in[12];
    const float* fc8c_b = (const float*)d_in[13];
    const float* fc8d_w = (const float*)d_in[14];
    const float* fc8d_b = (const float*)d_in[15];

    float* out = (float*)d_out;
    char* ws = (char*)d_ws;

    // layout: [0,*) x32 (5MB, phases 1-4) -> pooled (37.75MB) -> h7 (33.5MB)
    //         [37748736,*) h6 (75.5MB); small buffers after SB
    const size_t OFF_X32    = 0;
    const size_t OFF_POOLED = 0;
    const size_t OFF_H7     = 0;
    const size_t OFF_H6     = 37748736;
    const size_t SB         = 113246208;
    const size_t OFF_KEY    = SB;
    const size_t OFF_CNT    = SB + 90112;
    const size_t OFF_SORT   = SB + 180224;
    const size_t OFF_BOXD   = SB + 188416;
    const size_t OFF_LC     = SB + 253952;
    const size_t OFF_LD     = SB + 581632;
    const size_t OFF_SCD    = SB + 909312;
    const size_t OFF_CMAX   = SB + 1236992;
    const size_t OFF_CSUM   = SB + 1237504;

    float*  x32    = (float*)(ws + OFF_X32);
    float*  pooled = (float*)(ws + OFF_POOLED);
    float*  h6     = (float*)(ws + OFF_H6);
    float*  h7     = (float*)(ws + OFF_H7);
    float*  key    = (float*)(ws + OFF_KEY);
    int*    cnt    = (int*)(ws + OFF_CNT);
    int*    sorted = (int*)(ws + OFF_SORT);
    double* boxd   = (double*)(ws + OFF_BOXD);
    double* lc     = (double*)(ws + OFF_LC);
    double* ld     = (double*)(ws + OFF_LD);
    double* scd    = (double*)(ws + OFF_SCD);
    double* cmax   = (double*)(ws + OFF_CMAX);
    double* csum   = (double*)(ws + OFF_CSUM);

    float* outScores = out + NCL;
    float* outBoxes  = out + NCL + KTOP * NCL;

    // 1. conv2x2 + relu -> x32 (f32 exact chains)
    conv_chain_kernel<<<dim3(625, 2), 256, 0, stream>>>(features, rpn_w, rpn_b, x32);

    // 2. objectness f32 sigmoid keys
    obj_chain_kernel<<<dim3(88), 256, 0, stream>>>(x32, cls_w, cls_b, key);

    // 3. exact top-K on (key desc, idx asc)
    hipMemsetAsync(cnt, 0, NOBJ * sizeof(int), stream);
    topk_count_kernel<<<dim3(88, 11), 256, 0, stream>>>(key, cnt);
    topk_scatter_kernel<<<dim3(88), 256, 0, stream>>>(cnt, sorted);

    // 4. box regression + transform
    boxes_kernel<<<dim3(8), 256, 0, stream>>>(sorted, x32, reg_w, reg_b, boxd, outBoxes);

    // 5. ROI align -> pooled
    roi_kernel<<<dim3(KTOP), 256, 0, stream>>>(features, boxd, pooled);

    // 6. fc6: [2048,4608]x[4608,9216] + relu
    sgemm128_kernel<true><<<dim3(72, 16), 256, 0, stream>>>(pooled, fc6_w, fc6_b, h6,
                                                            2048, 9216, 4608);
    // 7. fc7: [2048,9216]x[9216,4096] + relu
    sgemm128_kernel<true><<<dim3(32, 16), 256, 0, stream>>>(h6, fc7_w, fc7_b, h7,
                                                            2048, 4096, 9216);
    // 8. fc8 both streams (fp64 acc)
    fc8_kernel<<<dim3(KTOP), 256, 0, stream>>>(h7, fc8c_w, fc8c_b, fc8d_w, fc8d_b, lc, ld);

    // 9. softmaxes + scores + clipped colsum
    colstats_kernel<<<dim3(NCL), 256, 0, stream>>>(lc, cmax, csum);
    scores_kernel<<<dim3(8), 256, 0, stream>>>(lc, ld, cmax, csum, scd, outScores);
    colsum_kernel<<<dim3(NCL), 256, 0, stream>>>(scd, out);
}

// Round 3
// 2262.602 us; speedup vs baseline: 2.4321x; 2.4321x over previous
//
#include <hip/hip_runtime.h>
#include <math.h>

// ---------------------------------------------------------------------------
// WeaklySupervisedDetection
//   Phases 1-4 (conv/obj/topk/boxes): f32-bit-exact chains — DO NOT TOUCH,
//   they reproduce the np reference's ordering (R2: absmax 2.4e-7).
//   FC trunk: bf16 MFMA (16x16x32) m97-style GEMM, weights transposed to
//   [N,K] bf16 on the fly. fc8/softmax stay fp64 (loose thresholds anyway).
// ---------------------------------------------------------------------------

#define HN 50
#define WN 50
#define CN 512
#define AN 9
#define KTOP 2048
#define NCL 20
#define NOBJ 22500  // H*W*A

typedef unsigned short ushort_t;
typedef __attribute__((ext_vector_type(8))) short short8;
typedef __attribute__((ext_vector_type(4))) float floatx4;

__device__ __forceinline__ ushort_t bf16_rne(float f) {
    unsigned int u = __float_as_uint(f);
    unsigned int r = (u + 0x7FFFu + ((u >> 16) & 1u)) >> 16;
    return (ushort_t)r;
}

__device__ __forceinline__ void gl_lds16(const void* g, void* l) {
    __builtin_amdgcn_global_load_lds(
        (const __attribute__((address_space(1))) unsigned int*)g,
        (__attribute__((address_space(3))) unsigned int*)l, 16, 0, 0);
}

// ---------------- conv 2x2 SAME, exact f32 tap chains ----------------------
__launch_bounds__(256)
__global__ void conv_chain_kernel(const float* __restrict__ feat,
                                  const float* __restrict__ rpnw,
                                  const float* __restrict__ rpnb,
                                  float* __restrict__ x32)
{
    __shared__ float xs[16 * 512];  // [hwLocal(4)][tap(4)][cin(512)]
    const int tid = threadIdx.x;
    const int hwBase = blockIdx.x * 4;
    const int co = blockIdx.y * 256 + tid;

    for (int t = tid; t < 16 * 512; t += 256) {
        int slot = t >> 9, c = t & 511;
        int hwL = slot >> 2, tap = slot & 3;
        int hw = hwBase + hwL;
        int h = hw / WN, w = hw % WN;
        int hy = h + (tap >> 1), wx = w + (tap & 1);
        float v = 0.f;
        if (hy < HN && wx < WN) v = feat[(size_t)(hy * WN + wx) * CN + c];
        xs[t] = v;
    }
    __syncthreads();

    float acc[4][4];
#pragma unroll
    for (int i = 0; i < 4; i++)
#pragma unroll
        for (int t = 0; t < 4; t++) acc[i][t] = 0.f;

    for (int c = 0; c < CN; c++) {
        float wv0 = rpnw[(size_t)(0 * CN + c) * CN + co];
        float wv1 = rpnw[(size_t)(1 * CN + c) * CN + co];
        float wv2 = rpnw[(size_t)(2 * CN + c) * CN + co];
        float wv3 = rpnw[(size_t)(3 * CN + c) * CN + co];
#pragma unroll
        for (int i = 0; i < 4; i++) {
            acc[i][0] = fmaf(xs[(i * 4 + 0) * 512 + c], wv0, acc[i][0]);
            acc[i][1] = fmaf(xs[(i * 4 + 1) * 512 + c], wv1, acc[i][1]);
            acc[i][2] = fmaf(xs[(i * 4 + 2) * 512 + c], wv2, acc[i][2]);
            acc[i][3] = fmaf(xs[(i * 4 + 3) * 512 + c], wv3, acc[i][3]);
        }
    }
    float b = rpnb[co];
#pragma unroll
    for (int i = 0; i < 4; i++) {
        float v = ((acc[i][0] + acc[i][1]) + acc[i][2]) + acc[i][3];
        v = v + b;
        v = v > 0.f ? v : 0.f;
        x32[(size_t)(hwBase + i) * CN + co] = v;
    }
}

// ---------------- objectness: f32 chain -> f32 sigmoid key ------------------
__launch_bounds__(256)
__global__ void obj_chain_kernel(const float* __restrict__ x32,
                                 const float* __restrict__ clsw,
                                 const float* __restrict__ clsb,
                                 float* __restrict__ key)
{
    int i = blockIdx.x * 256 + threadIdx.x;
    if (i >= NOBJ) return;
    int hw = i / AN, a = i % AN;
    const float* xr = x32 + (size_t)hw * CN;
    float acc = 0.f;
    for (int c = 0; c < CN; c++) acc = fmaf(xr[c], clsw[c * AN + a], acc);
    float l32 = acc + clsb[a];
    float s32 = (float)(1.0 / (1.0 + exp(-(double)l32)));
    key[i] = s32;
}

// ---------------- exact top-K rank count on (f32 key desc, idx asc) --------
__launch_bounds__(256)
__global__ void topk_count_kernel(const float* __restrict__ key, int* __restrict__ cnt)
{
    __shared__ float ch[2048];
    int tid = threadIdx.x;
    int j0 = blockIdx.y * 2048;
    for (int t = tid; t < 2048; t += 256) {
        int jg = j0 + t;
        ch[t] = (jg < NOBJ) ? key[jg] : -1.0f;
    }
    int i = blockIdx.x * 256 + tid;
    float vi = (i < NOBJ) ? key[i] : 2.0f;
    __syncthreads();
    int c = 0;
    for (int t = 0; t < 2048; t++) {
        float vj = ch[t];
        int jg = j0 + t;
        c += (vj > vi || (vj == vi && jg < i)) ? 1 : 0;
    }
    if (i < NOBJ && c) atomicAdd(&cnt[i], c);
}

__launch_bounds__(256)
__global__ void topk_scatter_kernel(const int* __restrict__ cnt, int* __restrict__ sorted)
{
    int i = blockIdx.x * 256 + threadIdx.x;
    if (i < NOBJ) {
        int r = cnt[i];
        if (r < KTOP) sorted[r] = i;
    }
}

// ---------------- box regression (f32 chains) + transform (fp64) -----------
__launch_bounds__(256)
__global__ void boxes_kernel(const int* __restrict__ sorted,
                             const float* __restrict__ x32,
                             const float* __restrict__ regw,
                             const float* __restrict__ regb,
                             double* __restrict__ boxd,
                             float* __restrict__ outBoxes)
{
    int k = blockIdx.x * 256 + threadIdx.x;
    if (k >= KTOP) return;
    int i = sorted[k];
    int hw = i / AN, a = i % AN;
    const float* xr = x32 + (size_t)hw * CN;
    float r0 = 0.f, r1 = 0.f, r2 = 0.f, r3 = 0.f;
    for (int c = 0; c < CN; c++) {
        float xv = xr[c];
        const float* wr = regw + (size_t)c * (4 * AN) + 4 * a;
        r0 = fmaf(xv, wr[0], r0);
        r1 = fmaf(xv, wr[1], r1);
        r2 = fmaf(xv, wr[2], r2);
        r3 = fmaf(xv, wr[3], r3);
    }
    r0 = r0 + regb[4 * a + 0];
    r1 = r1 + regb[4 * a + 1];
    r2 = r2 + regb[4 * a + 2];
    r3 = r3 + regb[4 * a + 3];
    double s0 = 1.0 / (1.0 + exp(-(double)r0));
    double s1 = 1.0 / (1.0 + exp(-(double)r1));
    double s2 = 1.0 / (1.0 + exp(-(double)r2));
    double s3 = 1.0 / (1.0 + exp(-(double)r3));
    double x1 = s0 * (double)(WN - 2);
    double x2 = x1 + 1.0 + s1 * ((double)(WN - 1) - x1);
    double y1 = s2 * (double)(HN - 2);
    double y2 = y1 + 1.0 + s3 * ((double)(HN - 1) - y1);
    boxd[4 * k + 0] = x1; boxd[4 * k + 1] = x2;
    boxd[4 * k + 2] = y1; boxd[4 * k + 3] = y2;
    outBoxes[4 * k + 0] = (float)x1; outBoxes[4 * k + 1] = (float)x2;
    outBoxes[4 * k + 2] = (float)y1; outBoxes[4 * k + 3] = (float)y2;
}

// ---------------- ROI align -> pooled [K, 4608] (bf16) ---------------------
__launch_bounds__(256)
__global__ void roi_kernel(const float* __restrict__ feat,
                           const double* __restrict__ boxd,
                           ushort_t* __restrict__ pooled)
{
    int k = blockIdx.x;
    int tid = threadIdx.x;
    double x1 = boxd[4 * k + 0], x2 = boxd[4 * k + 1];
    double y1 = boxd[4 * k + 2], y2 = boxd[4 * k + 3];
    int ix0[3], ix1[3], iy0[3], iy1[3];
    double fx[3], fy[3];
#pragma unroll
    for (int p = 0; p < 3; p++) {
        double t = ((double)p + 0.5) / 3.0;
        double xsv = x1 + (x2 - x1) * t;
        double x0f = floor(xsv);
        fx[p] = xsv - x0f;
        int xi = (int)x0f;
        xi = xi < 0 ? 0 : (xi > WN - 1 ? WN - 1 : xi);
        ix0[p] = xi;
        ix1[p] = (xi + 1 > WN - 1) ? WN - 1 : xi + 1;
        double ysv = y1 + (y2 - y1) * t;
        double y0f = floor(ysv);
        fy[p] = ysv - y0f;
        int yi = (int)y0f;
        yi = yi < 0 ? 0 : (yi > HN - 1 ? HN - 1 : yi);
        iy0[p] = yi;
        iy1[p] = (yi + 1 > HN - 1) ? HN - 1 : yi + 1;
    }
#pragma unroll
    for (int pp = 0; pp < 9; pp++) {
        int py = pp / 3, px = pp % 3;
        double w00 = (1.0 - fy[py]) * (1.0 - fx[px]);
        double w01 = (1.0 - fy[py]) * fx[px];
        double w10 = fy[py] * (1.0 - fx[px]);
        double w11 = fy[py] * fx[px];
        const float* f00 = feat + (size_t)(iy0[py] * WN + ix0[px]) * CN;
        const float* f01 = feat + (size_t)(iy0[py] * WN + ix1[px]) * CN;
        const float* f10 = feat + (size_t)(iy1[py] * WN + ix0[px]) * CN;
        const float* f11 = feat + (size_t)(iy1[py] * WN + ix1[px]) * CN;
        ushort_t* dst = pooled + ((size_t)k * 9 + pp) * CN;
        for (int c = tid; c < CN; c += 256) {
            double v = w00 * (double)f00[c] + w01 * (double)f01[c]
                     + w10 * (double)f10[c] + w11 * (double)f11[c];
            dst[c] = bf16_rne((float)v);
        }
    }
}

// ---------------- transpose + cvt: W fp32 [K,N] cols [n0,n0+Nsub) ----------
//                  -> Wt bf16 [Nsub][K]
__launch_bounds__(256)
__global__ void transpose_cvt_kernel(const float* __restrict__ W,
                                     ushort_t* __restrict__ Wt,
                                     int K, int N, int n0)
{
    __shared__ float tile[64][65];
    const int tid = threadIdx.x;
    const int k0 = blockIdx.x * 64;
    const int nb = blockIdx.y * 64;
#pragma unroll
    for (int q = 0; q < 4; q++) {
        int r = (tid >> 4) + q * 16;
        int c = (tid & 15) * 4;
        float4 v = *(const float4*)&W[(size_t)(k0 + r) * N + n0 + nb + c];
        tile[r][c + 0] = v.x; tile[r][c + 1] = v.y;
        tile[r][c + 2] = v.z; tile[r][c + 3] = v.w;
    }
    __syncthreads();
#pragma unroll
    for (int q = 0; q < 4; q++) {
        int rn = (tid >> 4) + q * 16;
        int ck = (tid & 15) * 4;
        ushort4 o;
        o.x = bf16_rne(tile[ck + 0][rn]);
        o.y = bf16_rne(tile[ck + 1][rn]);
        o.z = bf16_rne(tile[ck + 2][rn]);
        o.w = bf16_rne(tile[ck + 3][rn]);
        *(ushort4*)&Wt[(size_t)(nb + rn) * K + k0 + ck] = o;
    }
}

// ---------------- bf16 MFMA GEMM (m97 structure) ---------------------------
// A [M,K] bf16 row-major, Bt [Nsub,K] bf16 row-major (= B^T), C row stride Nc.
// Tile 128x128, BK=32, 4 waves x (4x4) 16x16x32 tiles. bias+relu epilogue.
// OUT_BF16: write bf16, else fp32.
template <bool OUT_BF16>
__launch_bounds__(256)
__global__ void gemm_bt_kernel(const ushort_t* __restrict__ A,
                               const ushort_t* __restrict__ Bt,
                               const float* __restrict__ bias,
                               void* __restrict__ Cv,
                               int Nc, int K)
{
    __shared__ ushort_t As[128 * 32];  // [m][k] 64 B/row
    __shared__ ushort_t Bs[128 * 32];  // [n][k]
    const int tid = threadIdx.x;
    const int w = tid >> 6, l = tid & 63;
    const int mBase = blockIdx.y * 128, nBase = blockIdx.x * 128;
    const int mW = (w >> 1) * 64, nW = (w & 1) * 64;

    floatx4 acc[4][4];
#pragma unroll
    for (int i = 0; i < 4; i++)
#pragma unroll
        for (int j = 0; j < 4; j++) acc[i][j] = (floatx4){0.f, 0.f, 0.f, 0.f};

    // staging addresses: flat byte f = (tid + pass*256)*16; row = f/64, col = f%64
    const int r0 = tid >> 2;            // pass0 row
    const int ce = (tid & 3) * 8;       // col in elements (8 bf16 = 16B)

    for (int kb = 0; kb < K; kb += 32) {
        __syncthreads();
        gl_lds16(&A[(size_t)(mBase + r0) * K + kb + ce], &As[tid * 8]);
        gl_lds16(&A[(size_t)(mBase + r0 + 64) * K + kb + ce], &As[2048 + tid * 8]);
        gl_lds16(&Bt[(size_t)(nBase + r0) * K + kb + ce], &Bs[tid * 8]);
        gl_lds16(&Bt[(size_t)(nBase + r0 + 64) * K + kb + ce], &Bs[2048 + tid * 8]);
        __syncthreads();

        short8 aF[4], bF[4];
#pragma unroll
        for (int i = 0; i < 4; i++)
            aF[i] = *(const short8*)&As[(mW + i * 16 + (l & 15)) * 32 + (l >> 4) * 8];
#pragma unroll
        for (int j = 0; j < 4; j++)
            bF[j] = *(const short8*)&Bs[(nW + j * 16 + (l & 15)) * 32 + (l >> 4) * 8];
#pragma unroll
        for (int i = 0; i < 4; i++)
#pragma unroll
            for (int j = 0; j < 4; j++)
                acc[i][j] = __builtin_amdgcn_mfma_f32_16x16x32_bf16(aF[i], bF[j], acc[i][j], 0, 0, 0);
    }

    // epilogue: row = (l>>4)*4 + r, col = l&15 within each 16x16 tile
#pragma unroll
    for (int i = 0; i < 4; i++) {
        int rowT = mBase + mW + i * 16 + (l >> 4) * 4;
#pragma unroll
        for (int j = 0; j < 4; j++) {
            int col = nBase + nW + j * 16 + (l & 15);
            float bv = bias[col];
#pragma unroll
            for (int r = 0; r < 4; r++) {
                float v = acc[i][j][r] + bv;
                v = v > 0.f ? v : 0.f;
                size_t idx = (size_t)(rowT + r) * Nc + col;
                if (OUT_BF16) ((ushort_t*)Cv)[idx] = bf16_rne(v);
                else ((float*)Cv)[idx] = v;
            }
        }
    }
}

// ---------------- fc8 (both streams), fp64 accumulate -----------------------
__launch_bounds__(256)
__global__ void fc8_kernel(const float* __restrict__ h7,
                           const float* __restrict__ cw, const float* __restrict__ cb,
                           const float* __restrict__ dw, const float* __restrict__ db,
                           double* __restrict__ lc, double* __restrict__ ld)
{
    __shared__ float hrow[4096];
    __shared__ double red[8];
    int i = blockIdx.x;
    int tid = threadIdx.x;
    for (int j = tid; j < 4096; j += 256) hrow[j] = h7[(size_t)i * 4096 + j];
    __syncthreads();
    for (int o = 0; o < NCL; o++) {
        double sc = 0.0, sd = 0.0;
        for (int j = tid; j < 4096; j += 256) {
            double hv = (double)hrow[j];
            sc += hv * (double)cw[(size_t)j * NCL + o];
            sd += hv * (double)dw[(size_t)j * NCL + o];
        }
        for (int off = 32; off > 0; off >>= 1) {
            sc += __shfl_down(sc, off, 64);
            sd += __shfl_down(sd, off, 64);
        }
        int wid = tid >> 6, lane = tid & 63;
        if (lane == 0) { red[wid] = sc; red[4 + wid] = sd; }
        __syncthreads();
        if (tid == 0) {
            lc[(size_t)i * NCL + o] = red[0] + red[1] + red[2] + red[3] + (double)cb[o];
            ld[(size_t)i * NCL + o] = red[4] + red[5] + red[6] + red[7] + (double)db[o];
        }
        __syncthreads();
    }
}

// ---------------- softmax column stats (axis=0 over 2048 regions) ----------
__launch_bounds__(256)
__global__ void colstats_kernel(const double* __restrict__ lc,
                                double* __restrict__ cmax, double* __restrict__ csum)
{
    __shared__ double red[4];
    int j = blockIdx.x, tid = threadIdx.x;
    double m = -1.0e300;
    for (int i = tid; i < KTOP; i += 256) m = fmax(m, lc[(size_t)i * NCL + j]);
    for (int off = 32; off > 0; off >>= 1) m = fmax(m, __shfl_down(m, off, 64));
    if ((tid & 63) == 0) red[tid >> 6] = m;
    __syncthreads();
    double mm = fmax(fmax(red[0], red[1]), fmax(red[2], red[3]));
    __syncthreads();
    double s = 0.0;
    for (int i = tid; i < KTOP; i += 256) s += exp(lc[(size_t)i * NCL + j] - mm);
    for (int off = 32; off > 0; off >>= 1) s += __shfl_down(s, off, 64);
    if ((tid & 63) == 0) red[tid >> 6] = s;
    __syncthreads();
    if (tid == 0) { cmax[j] = mm; csum[j] = red[0] + red[1] + red[2] + red[3]; }
}

// ---------------- row softmax + scores ---------------------------------------
__launch_bounds__(256)
__global__ void scores_kernel(const double* __restrict__ lc, const double* __restrict__ ld,
                              const double* __restrict__ cmax, const double* __restrict__ csum,
                              double* __restrict__ scd, float* __restrict__ outScores)
{
    int i = blockIdx.x * 256 + threadIdx.x;
    if (i >= KTOP) return;
    const double* lr = ld + (size_t)i * NCL;
    double rm = -1.0e300;
#pragma unroll
    for (int j = 0; j < NCL; j++) rm = fmax(rm, lr[j]);
    double rs = 0.0;
#pragma unroll
    for (int j = 0; j < NCL; j++) rs += exp(lr[j] - rm);
#pragma unroll
    for (int j = 0; j < NCL; j++) {
        double cc = exp(lc[(size_t)i * NCL + j] - cmax[j]) / csum[j];
        double dd = exp(lr[j] - rm) / rs;
        double sc = cc * dd;
        scd[(size_t)i * NCL + j] = sc;
        outScores[(size_t)i * NCL + j] = (float)sc;
    }
}

// ---------------- column sum + clip -----------------------------------------
__launch_bounds__(256)
__global__ void colsum_kernel(const double* __restrict__ scd, float* __restrict__ out)
{
    __shared__ double red[4];
    int j = blockIdx.x, tid = threadIdx.x;
    double s = 0.0;
    for (int i = tid; i < KTOP; i += 256) s += scd[(size_t)i * NCL + j];
    for (int off = 32; off > 0; off >>= 1) s += __shfl_down(s, off, 64);
    if ((tid & 63) == 0) red[tid >> 6] = s;
    __syncthreads();
    if (tid == 0) {
        double t = red[0] + red[1] + red[2] + red[3];
        t = t < 0.0 ? 0.0 : (t > 1.0 ? 1.0 : t);
        out[j] = (float)t;
    }
}

// ---------------------------------------------------------------------------
extern "C" void kernel_launch(void* const* d_in, const int* in_sizes, int n_in,
                              void* d_out, int out_size, void* d_ws, size_t ws_size,
                              hipStream_t stream)
{
    const float* features = (const float*)d_in[0];
    const float* rpn_w  = (const float*)d_in[2];
    const float* rpn_b  = (const float*)d_in[3];
    const float* cls_w  = (const float*)d_in[4];
    const float* cls_b  = (const float*)d_in[5];
    const float* reg_w  = (const float*)d_in[6];
    const float* reg_b  = (const float*)d_in[7];
    const float* fc6_w  = (const float*)d_in[8];
    const float* fc6_b  = (const float*)d_in[9];
    const float* fc7_w  = (const float*)d_in[10];
    const float* fc7_b  = (const float*)d_in[11];
    const float* fc8c_w = (const float*)d_in[12];
    const float* fc8c_b = (const float*)d_in[13];
    const float* fc8d_w = (const float*)d_in[14];
    const float* fc8d_b = (const float*)d_in[15];

    float* out = (float*)d_out;
    char* ws = (char*)d_ws;

    // ---- workspace layout (phase-overlapped; peak ~113.8 MB) ----
    // [0, 37,748,736)            h6bf (bf16 2048x9216); aliased early by x32,
    //                            key/cnt/sorted/boxd (all dead before GEMM1)
    // [37,748,736, 80,216,064)   WtBuf: Wt6 halves (42.47MB) then Wt7 halves
    //                            (37.75MB); tail aliased late by lc/ld/scd
    // [80,216,064, 99,090,432)   Abf (bf16 pooled 2048x4608), dead after GEMM1
    // [80,216,064, 113,770,496)  h7 (fp32 2048x4096) — written in GEMM2,
    //                            overlaps dead Abf
    const size_t OFF_H6   = 0;
    const size_t OFF_WT   = 37748736;
    const size_t OFF_ABF  = 80216064;
    const size_t OFF_H7   = 80216064;
    // early smalls (inside h6bf region, dead before GEMM1):
    const size_t OFF_X32  = 0;                   // 5,120,000
    const size_t OFF_KEY  = 5120000;             // 90,000 -> pad 90,112
    const size_t OFF_CNT  = 5210112;             // 90,000 -> 90,112
    const size_t OFF_SORT = 5300224;             // 8,192
    const size_t OFF_BOXD = 5308416;             // 65,536
    // late smalls (inside WtBuf tail [75,497,472, 80,216,064), Wt7 uses only
    // 37.75MB of WtBuf so this tail is free during GEMM2; written at fc8):
    const size_t OFF_LC   = OFF_WT + 37748736;          // 327,680
    const size_t OFF_LD   = OFF_LC + 327680;            // 327,680
    const size_t OFF_SCD  = OFF_LD + 327680;            // 327,680
    const size_t OFF_CMAX = OFF_SCD + 327680;           // 512
    const size_t OFF_CSUM = OFF_CMAX + 512;             // 512

    float*    x32    = (float*)(ws + OFF_X32);
    float*    key    = (float*)(ws + OFF_KEY);
    int*      cnt    = (int*)(ws + OFF_CNT);
    int*      sorted = (int*)(ws + OFF_SORT);
    double*   boxd   = (double*)(ws + OFF_BOXD);
    ushort_t* Abf    = (ushort_t*)(ws + OFF_ABF);
    ushort_t* Wt     = (ushort_t*)(ws + OFF_WT);
    ushort_t* h6bf   = (ushort_t*)(ws + OFF_H6);
    float*    h7     = (float*)(ws + OFF_H7);
    double*   lc     = (double*)(ws + OFF_LC);
    double*   ld     = (double*)(ws + OFF_LD);
    double*   scd    = (double*)(ws + OFF_SCD);
    double*   cmax   = (double*)(ws + OFF_CMAX);
    double*   csum   = (double*)(ws + OFF_CSUM);

    float* outScores = out + NCL;
    float* outBoxes  = out + NCL + KTOP * NCL;

    // 1-4: bit-exact RPN path (unchanged from R2-passing version)
    conv_chain_kernel<<<dim3(625, 2), 256, 0, stream>>>(features, rpn_w, rpn_b, x32);
    obj_chain_kernel<<<dim3(88), 256, 0, stream>>>(x32, cls_w, cls_b, key);
    hipMemsetAsync(cnt, 0, NOBJ * sizeof(int), stream);
    topk_count_kernel<<<dim3(88, 11), 256, 0, stream>>>(key, cnt);
    topk_scatter_kernel<<<dim3(88), 256, 0, stream>>>(cnt, sorted);
    boxes_kernel<<<dim3(8), 256, 0, stream>>>(sorted, x32, reg_w, reg_b, boxd, outBoxes);

    // 5: ROI align -> Abf (bf16)
    roi_kernel<<<dim3(KTOP), 256, 0, stream>>>(features, boxd, Abf);

    // 6: fc6 = Abf[2048,4608] x fc6_w[4608,9216] (+relu) -> h6bf, two N-halves
    //    DIN=4608, N=9216; half Nsub=4608
    transpose_cvt_kernel<<<dim3(72, 72), 256, 0, stream>>>(fc6_w, Wt, 4608, 9216, 0);
    gemm_bt_kernel<true><<<dim3(36, 16), 256, 0, stream>>>(Abf, Wt, fc6_b + 0,
                                                           (void*)(h6bf + 0), 9216, 4608);
    transpose_cvt_kernel<<<dim3(72, 72), 256, 0, stream>>>(fc6_w, Wt, 4608, 9216, 4608);
    gemm_bt_kernel<true><<<dim3(36, 16), 256, 0, stream>>>(Abf, Wt, fc6_b + 4608,
                                                           (void*)(h6bf + 4608), 9216, 4608);

    // 7: fc7 = h6bf[2048,9216] x fc7_w[9216,4096] (+relu) -> h7 fp32, two halves
    transpose_cvt_kernel<<<dim3(144, 32), 256, 0, stream>>>(fc7_w, Wt, 9216, 4096, 0);
    gemm_bt_kernel<false><<<dim3(16, 16), 256, 0, stream>>>(h6bf, Wt, fc7_b + 0,
                                                            (void*)(h7 + 0), 4096, 9216);
    transpose_cvt_kernel<<<dim3(144, 32), 256, 0, stream>>>(fc7_w, Wt, 9216, 4096, 2048);
    gemm_bt_kernel<false><<<dim3(16, 16), 256, 0, stream>>>(h6bf, Wt, fc7_b + 2048,
                                                            (void*)(h7 + 2048), 4096, 9216);

    // 8: fc8 both streams (fp64 acc)
    fc8_kernel<<<dim3(KTOP), 256, 0, stream>>>(h7, fc8c_w, fc8c_b, fc8d_w, fc8d_b, lc, ld);

    // 9: softmaxes + scores + clipped colsum
    colstats_kernel<<<dim3(NCL), 256, 0, stream>>>(lc, cmax, csum);
    scores_kernel<<<dim3(8), 256, 0, stream>>>(lc, ld, cmax, csum, scd, outScores);
    colsum_kernel<<<dim3(NCL), 256, 0, stream>>>(scd, out);
}

// Round 4
// 1598.598 us; speedup vs baseline: 3.4423x; 1.4154x over previous
//
#include <hip/hip_runtime.h>
#include <math.h>

// ---------------------------------------------------------------------------
// WeaklySupervisedDetection
//   Phases 1-4 (conv/obj/topk/boxes): f32-bit-exact chains — DO NOT TOUCH,
//   they reproduce the np reference's ordering (R2: absmax 2.4e-7).
//   FC trunk + fc8: bf16 MFMA (16x16x32) m97-style GEMMs.
//   Softmaxes: fp64 math over fp32 logits (tiny kernels).
// ---------------------------------------------------------------------------

#define HN 50
#define WN 50
#define CN 512
#define AN 9
#define KTOP 2048
#define NCL 20
#define NOBJ 22500  // H*W*A

typedef unsigned short ushort_t;
typedef __attribute__((ext_vector_type(8))) short short8;
typedef __attribute__((ext_vector_type(4))) float floatx4;

__device__ __forceinline__ ushort_t bf16_rne(float f) {
    unsigned int u = __float_as_uint(f);
    unsigned int r = (u + 0x7FFFu + ((u >> 16) & 1u)) >> 16;
    return (ushort_t)r;
}

__device__ __forceinline__ void gl_lds16(const void* g, void* l) {
    __builtin_amdgcn_global_load_lds(
        (const __attribute__((address_space(1))) unsigned int*)g,
        (__attribute__((address_space(3))) unsigned int*)l, 16, 0, 0);
}

// ---------------- conv 2x2 SAME, exact f32 tap chains ----------------------
__launch_bounds__(256)
__global__ void conv_chain_kernel(const float* __restrict__ feat,
                                  const float* __restrict__ rpnw,
                                  const float* __restrict__ rpnb,
                                  float* __restrict__ x32)
{
    __shared__ float xs[16 * 512];  // [hwLocal(4)][tap(4)][cin(512)]
    const int tid = threadIdx.x;
    const int hwBase = blockIdx.x * 4;
    const int co = blockIdx.y * 256 + tid;

    for (int t = tid; t < 16 * 512; t += 256) {
        int slot = t >> 9, c = t & 511;
        int hwL = slot >> 2, tap = slot & 3;
        int hw = hwBase + hwL;
        int h = hw / WN, w = hw % WN;
        int hy = h + (tap >> 1), wx = w + (tap & 1);
        float v = 0.f;
        if (hy < HN && wx < WN) v = feat[(size_t)(hy * WN + wx) * CN + c];
        xs[t] = v;
    }
    __syncthreads();

    float acc[4][4];
#pragma unroll
    for (int i = 0; i < 4; i++)
#pragma unroll
        for (int t = 0; t < 4; t++) acc[i][t] = 0.f;

    for (int c = 0; c < CN; c++) {
        float wv0 = rpnw[(size_t)(0 * CN + c) * CN + co];
        float wv1 = rpnw[(size_t)(1 * CN + c) * CN + co];
        float wv2 = rpnw[(size_t)(2 * CN + c) * CN + co];
        float wv3 = rpnw[(size_t)(3 * CN + c) * CN + co];
#pragma unroll
        for (int i = 0; i < 4; i++) {
            acc[i][0] = fmaf(xs[(i * 4 + 0) * 512 + c], wv0, acc[i][0]);
            acc[i][1] = fmaf(xs[(i * 4 + 1) * 512 + c], wv1, acc[i][1]);
            acc[i][2] = fmaf(xs[(i * 4 + 2) * 512 + c], wv2, acc[i][2]);
            acc[i][3] = fmaf(xs[(i * 4 + 3) * 512 + c], wv3, acc[i][3]);
        }
    }
    float b = rpnb[co];
#pragma unroll
    for (int i = 0; i < 4; i++) {
        float v = ((acc[i][0] + acc[i][1]) + acc[i][2]) + acc[i][3];
        v = v + b;
        v = v > 0.f ? v : 0.f;
        x32[(size_t)(hwBase + i) * CN + co] = v;
    }
}

// ---------------- objectness: f32 chain -> f32 sigmoid key ------------------
__launch_bounds__(256)
__global__ void obj_chain_kernel(const float* __restrict__ x32,
                                 const float* __restrict__ clsw,
                                 const float* __restrict__ clsb,
                                 float* __restrict__ key)
{
    int i = blockIdx.x * 256 + threadIdx.x;
    if (i >= NOBJ) return;
    int hw = i / AN, a = i % AN;
    const float* xr = x32 + (size_t)hw * CN;
    float acc = 0.f;
    for (int c = 0; c < CN; c++) acc = fmaf(xr[c], clsw[c * AN + a], acc);
    float l32 = acc + clsb[a];
    float s32 = (float)(1.0 / (1.0 + exp(-(double)l32)));
    key[i] = s32;
}

// ---------------- exact top-K rank count on (f32 key desc, idx asc) --------
__launch_bounds__(256)
__global__ void topk_count_kernel(const float* __restrict__ key, int* __restrict__ cnt)
{
    __shared__ float ch[2048];
    int tid = threadIdx.x;
    int j0 = blockIdx.y * 2048;
    for (int t = tid; t < 2048; t += 256) {
        int jg = j0 + t;
        ch[t] = (jg < NOBJ) ? key[jg] : -1.0f;
    }
    int i = blockIdx.x * 256 + tid;
    float vi = (i < NOBJ) ? key[i] : 2.0f;
    __syncthreads();
    int c = 0;
    for (int t = 0; t < 2048; t++) {
        float vj = ch[t];
        int jg = j0 + t;
        c += (vj > vi || (vj == vi && jg < i)) ? 1 : 0;
    }
    if (i < NOBJ && c) atomicAdd(&cnt[i], c);
}

__launch_bounds__(256)
__global__ void topk_scatter_kernel(const int* __restrict__ cnt, int* __restrict__ sorted)
{
    int i = blockIdx.x * 256 + threadIdx.x;
    if (i < NOBJ) {
        int r = cnt[i];
        if (r < KTOP) sorted[r] = i;
    }
}

// ---------------- box regression (f32 chains) + transform (fp64) -----------
__launch_bounds__(256)
__global__ void boxes_kernel(const int* __restrict__ sorted,
                             const float* __restrict__ x32,
                             const float* __restrict__ regw,
                             const float* __restrict__ regb,
                             double* __restrict__ boxd,
                             float* __restrict__ outBoxes)
{
    int k = blockIdx.x * 256 + threadIdx.x;
    if (k >= KTOP) return;
    int i = sorted[k];
    int hw = i / AN, a = i % AN;
    const float* xr = x32 + (size_t)hw * CN;
    float r0 = 0.f, r1 = 0.f, r2 = 0.f, r3 = 0.f;
    for (int c = 0; c < CN; c++) {
        float xv = xr[c];
        const float* wr = regw + (size_t)c * (4 * AN) + 4 * a;
        r0 = fmaf(xv, wr[0], r0);
        r1 = fmaf(xv, wr[1], r1);
        r2 = fmaf(xv, wr[2], r2);
        r3 = fmaf(xv, wr[3], r3);
    }
    r0 = r0 + regb[4 * a + 0];
    r1 = r1 + regb[4 * a + 1];
    r2 = r2 + regb[4 * a + 2];
    r3 = r3 + regb[4 * a + 3];
    double s0 = 1.0 / (1.0 + exp(-(double)r0));
    double s1 = 1.0 / (1.0 + exp(-(double)r1));
    double s2 = 1.0 / (1.0 + exp(-(double)r2));
    double s3 = 1.0 / (1.0 + exp(-(double)r3));
    double x1 = s0 * (double)(WN - 2);
    double x2 = x1 + 1.0 + s1 * ((double)(WN - 1) - x1);
    double y1 = s2 * (double)(HN - 2);
    double y2 = y1 + 1.0 + s3 * ((double)(HN - 1) - y1);
    boxd[4 * k + 0] = x1; boxd[4 * k + 1] = x2;
    boxd[4 * k + 2] = y1; boxd[4 * k + 3] = y2;
    outBoxes[4 * k + 0] = (float)x1; outBoxes[4 * k + 1] = (float)x2;
    outBoxes[4 * k + 2] = (float)y1; outBoxes[4 * k + 3] = (float)y2;
}

// ---------------- ROI align -> pooled [K, 4608] (bf16) ---------------------
__launch_bounds__(256)
__global__ void roi_kernel(const float* __restrict__ feat,
                           const double* __restrict__ boxd,
                           ushort_t* __restrict__ pooled)
{
    int k = blockIdx.x;
    int tid = threadIdx.x;
    double x1 = boxd[4 * k + 0], x2 = boxd[4 * k + 1];
    double y1 = boxd[4 * k + 2], y2 = boxd[4 * k + 3];
    int ix0[3], ix1[3], iy0[3], iy1[3];
    double fx[3], fy[3];
#pragma unroll
    for (int p = 0; p < 3; p++) {
        double t = ((double)p + 0.5) / 3.0;
        double xsv = x1 + (x2 - x1) * t;
        double x0f = floor(xsv);
        fx[p] = xsv - x0f;
        int xi = (int)x0f;
        xi = xi < 0 ? 0 : (xi > WN - 1 ? WN - 1 : xi);
        ix0[p] = xi;
        ix1[p] = (xi + 1 > WN - 1) ? WN - 1 : xi + 1;
        double ysv = y1 + (y2 - y1) * t;
        double y0f = floor(ysv);
        fy[p] = ysv - y0f;
        int yi = (int)y0f;
        yi = yi < 0 ? 0 : (yi > HN - 1 ? HN - 1 : yi);
        iy0[p] = yi;
        iy1[p] = (yi + 1 > HN - 1) ? HN - 1 : yi + 1;
    }
#pragma unroll
    for (int pp = 0; pp < 9; pp++) {
        int py = pp / 3, px = pp % 3;
        double w00 = (1.0 - fy[py]) * (1.0 - fx[px]);
        double w01 = (1.0 - fy[py]) * fx[px];
        double w10 = fy[py] * (1.0 - fx[px]);
        double w11 = fy[py] * fx[px];
        const float* f00 = feat + (size_t)(iy0[py] * WN + ix0[px]) * CN;
        const float* f01 = feat + (size_t)(iy0[py] * WN + ix1[px]) * CN;
        const float* f10 = feat + (size_t)(iy1[py] * WN + ix0[px]) * CN;
        const float* f11 = feat + (size_t)(iy1[py] * WN + ix1[px]) * CN;
        ushort_t* dst = pooled + ((size_t)k * 9 + pp) * CN;
        for (int c = tid; c < CN; c += 256) {
            double v = w00 * (double)f00[c] + w01 * (double)f01[c]
                     + w10 * (double)f10[c] + w11 * (double)f11[c];
            dst[c] = bf16_rne((float)v);
        }
    }
}

// ---------------- transpose + cvt: W fp32 [K,N] cols [n0,n0+Nsub) ----------
//                  -> Wt bf16 [Nsub][K]
__launch_bounds__(256)
__global__ void transpose_cvt_kernel(const float* __restrict__ W,
                                     ushort_t* __restrict__ Wt,
                                     int K, int N, int n0)
{
    __shared__ float tile[64][65];
    const int tid = threadIdx.x;
    const int k0 = blockIdx.x * 64;
    const int nb = blockIdx.y * 64;
#pragma unroll
    for (int q = 0; q < 4; q++) {
        int r = (tid >> 4) + q * 16;
        int c = (tid & 15) * 4;
        float4 v = *(const float4*)&W[(size_t)(k0 + r) * N + n0 + nb + c];
        tile[r][c + 0] = v.x; tile[r][c + 1] = v.y;
        tile[r][c + 2] = v.z; tile[r][c + 3] = v.w;
    }
    __syncthreads();
#pragma unroll
    for (int q = 0; q < 4; q++) {
        int rn = (tid >> 4) + q * 16;
        int ck = (tid & 15) * 4;
        ushort4 o;
        o.x = bf16_rne(tile[ck + 0][rn]);
        o.y = bf16_rne(tile[ck + 1][rn]);
        o.z = bf16_rne(tile[ck + 2][rn]);
        o.w = bf16_rne(tile[ck + 3][rn]);
        *(ushort4*)&Wt[(size_t)(nb + rn) * K + k0 + ck] = o;
    }
}

// ---------------- pack fc8 weights: [4096,20]x2 -> bf16 [128][4096] --------
__launch_bounds__(256)
__global__ void pack_w8_kernel(const float* __restrict__ cw,
                               const float* __restrict__ dw,
                               ushort_t* __restrict__ Wt8)
{
    int idx = blockIdx.x * 256 + threadIdx.x;  // 128*4096 total
    int n = idx >> 12, k = idx & 4095;
    float v = 0.f;
    if (n < NCL) v = cw[(size_t)k * NCL + n];
    else if (n < 2 * NCL) v = dw[(size_t)k * NCL + (n - NCL)];
    Wt8[(size_t)n * 4096 + k] = bf16_rne(v);
}

__launch_bounds__(128)
__global__ void pack_b8_kernel(const float* __restrict__ cb,
                               const float* __restrict__ db,
                               float* __restrict__ b8)
{
    int n = threadIdx.x;
    float v = 0.f;
    if (n < NCL) v = cb[n];
    else if (n < 2 * NCL) v = db[n - NCL];
    b8[n] = v;
}

// ---------------- bf16 MFMA GEMM (m97 structure) ---------------------------
// A [M,K] bf16 row-major, Bt [Nsub,K] bf16 row-major (= B^T), C row stride Nc.
// Tile 128x128, BK=32, 4 waves x (4x4) 16x16x32 tiles. bias(+relu) epilogue.
template <bool OUT_BF16, bool RELU>
__launch_bounds__(256)
__global__ void gemm_bt_kernel(const ushort_t* __restrict__ A,
                               const ushort_t* __restrict__ Bt,
                               const float* __restrict__ bias,
                               void* __restrict__ Cv,
                               int Nc, int K)
{
    __shared__ ushort_t As[128 * 32];  // [m][k] 64 B/row
    __shared__ ushort_t Bs[128 * 32];  // [n][k]
    const int tid = threadIdx.x;
    const int w = tid >> 6, l = tid & 63;
    const int mBase = blockIdx.y * 128, nBase = blockIdx.x * 128;
    const int mW = (w >> 1) * 64, nW = (w & 1) * 64;

    floatx4 acc[4][4];
#pragma unroll
    for (int i = 0; i < 4; i++)
#pragma unroll
        for (int j = 0; j < 4; j++) acc[i][j] = (floatx4){0.f, 0.f, 0.f, 0.f};

    const int r0 = tid >> 2;            // staging row
    const int ce = (tid & 3) * 8;       // staging col (8 bf16 = 16B)

    for (int kb = 0; kb < K; kb += 32) {
        __syncthreads();
        gl_lds16(&A[(size_t)(mBase + r0) * K + kb + ce], &As[tid * 8]);
        gl_lds16(&A[(size_t)(mBase + r0 + 64) * K + kb + ce], &As[2048 + tid * 8]);
        gl_lds16(&Bt[(size_t)(nBase + r0) * K + kb + ce], &Bs[tid * 8]);
        gl_lds16(&Bt[(size_t)(nBase + r0 + 64) * K + kb + ce], &Bs[2048 + tid * 8]);
        __syncthreads();

        short8 aF[4], bF[4];
#pragma unroll
        for (int i = 0; i < 4; i++)
            aF[i] = *(const short8*)&As[(mW + i * 16 + (l & 15)) * 32 + (l >> 4) * 8];
#pragma unroll
        for (int j = 0; j < 4; j++)
            bF[j] = *(const short8*)&Bs[(nW + j * 16 + (l & 15)) * 32 + (l >> 4) * 8];
#pragma unroll
        for (int i = 0; i < 4; i++)
#pragma unroll
            for (int j = 0; j < 4; j++)
                acc[i][j] = __builtin_amdgcn_mfma_f32_16x16x32_bf16(aF[i], bF[j], acc[i][j], 0, 0, 0);
    }

#pragma unroll
    for (int i = 0; i < 4; i++) {
        int rowT = mBase + mW + i * 16 + (l >> 4) * 4;
#pragma unroll
        for (int j = 0; j < 4; j++) {
            int col = nBase + nW + j * 16 + (l & 15);
            float bv = bias[col];
#pragma unroll
            for (int r = 0; r < 4; r++) {
                float v = acc[i][j][r] + bv;
                if (RELU) v = v > 0.f ? v : 0.f;
                size_t idx = (size_t)(rowT + r) * Nc + col;
                if (OUT_BF16) ((ushort_t*)Cv)[idx] = bf16_rne(v);
                else ((float*)Cv)[idx] = v;
            }
        }
    }
}

// ---------------- softmax column stats over fp32 logits --------------------
// logits layout: [KTOP][128]; cols 0..19 = c-stream, 20..39 = d-stream
__launch_bounds__(256)
__global__ void colstats_kernel(const float* __restrict__ logits,
                                double* __restrict__ cmax, double* __restrict__ csum)
{
    __shared__ double red[4];
    int j = blockIdx.x, tid = threadIdx.x;
    double m = -1.0e300;
    for (int i = tid; i < KTOP; i += 256) m = fmax(m, (double)logits[(size_t)i * 128 + j]);
    for (int off = 32; off > 0; off >>= 1) m = fmax(m, __shfl_down(m, off, 64));
    if ((tid & 63) == 0) red[tid >> 6] = m;
    __syncthreads();
    double mm = fmax(fmax(red[0], red[1]), fmax(red[2], red[3]));
    __syncthreads();
    double s = 0.0;
    for (int i = tid; i < KTOP; i += 256) s += exp((double)logits[(size_t)i * 128 + j] - mm);
    for (int off = 32; off > 0; off >>= 1) s += __shfl_down(s, off, 64);
    if ((tid & 63) == 0) red[tid >> 6] = s;
    __syncthreads();
    if (tid == 0) { cmax[j] = mm; csum[j] = red[0] + red[1] + red[2] + red[3]; }
}

// ---------------- row softmax + scores ---------------------------------------
__launch_bounds__(256)
__global__ void scores_kernel(const float* __restrict__ logits,
                              const double* __restrict__ cmax, const double* __restrict__ csum,
                              double* __restrict__ scd, float* __restrict__ outScores)
{
    int i = blockIdx.x * 256 + threadIdx.x;
    if (i >= KTOP) return;
    const float* lr = logits + (size_t)i * 128;
    double rm = -1.0e300;
#pragma unroll
    for (int j = 0; j < NCL; j++) rm = fmax(rm, (double)lr[NCL + j]);
    double rs = 0.0;
#pragma unroll
    for (int j = 0; j < NCL; j++) rs += exp((double)lr[NCL + j] - rm);
#pragma unroll
    for (int j = 0; j < NCL; j++) {
        double cc = exp((double)lr[j] - cmax[j]) / csum[j];
        double dd = exp((double)lr[NCL + j] - rm) / rs;
        double sc = cc * dd;
        scd[(size_t)i * NCL + j] = sc;
        outScores[(size_t)i * NCL + j] = (float)sc;
    }
}

// ---------------- column sum + clip -----------------------------------------
__launch_bounds__(256)
__global__ void colsum_kernel(const double* __restrict__ scd, float* __restrict__ out)
{
    __shared__ double red[4];
    int j = blockIdx.x, tid = threadIdx.x;
    double s = 0.0;
    for (int i = tid; i < KTOP; i += 256) s += scd[(size_t)i * NCL + j];
    for (int off = 32; off > 0; off >>= 1) s += __shfl_down(s, off, 64);
    if ((tid & 63) == 0) red[tid >> 6] = s;
    __syncthreads();
    if (tid == 0) {
        double t = red[0] + red[1] + red[2] + red[3];
        t = t < 0.0 ? 0.0 : (t > 1.0 ? 1.0 : t);
        out[j] = (float)t;
    }
}

// ---------------------------------------------------------------------------
extern "C" void kernel_launch(void* const* d_in, const int* in_sizes, int n_in,
                              void* d_out, int out_size, void* d_ws, size_t ws_size,
                              hipStream_t stream)
{
    const float* features = (const float*)d_in[0];
    const float* rpn_w  = (const float*)d_in[2];
    const float* rpn_b  = (const float*)d_in[3];
    const float* cls_w  = (const float*)d_in[4];
    const float* cls_b  = (const float*)d_in[5];
    const float* reg_w  = (const float*)d_in[6];
    const float* reg_b  = (const float*)d_in[7];
    const float* fc6_w  = (const float*)d_in[8];
    const float* fc6_b  = (const float*)d_in[9];
    const float* fc7_w  = (const float*)d_in[10];
    const float* fc7_b  = (const float*)d_in[11];
    const float* fc8c_w = (const float*)d_in[12];
    const float* fc8c_b = (const float*)d_in[13];
    const float* fc8d_w = (const float*)d_in[14];
    const float* fc8d_b = (const float*)d_in[15];

    float* out = (float*)d_out;
    char* ws = (char*)d_ws;

    // ---- workspace layout (phase-overlapped; peak ~99 MB) ----
    // [0, 37,748,736)            h6bf (bf16 2048x9216); aliased early by
    //                            x32/key/cnt/sorted/boxd (dead before GEMM1)
    // [37,748,736, 80,216,064)   WtBuf (Wt6 42.47MB, then Wt7 37.75MB);
    //                            tail [75.5MB, 80.2MB) = late smalls
    // [80,216,064, 99,090,432)   Abf (bf16 pooled), then h7bf (16.8MB)
    const size_t OFF_H6   = 0;
    const size_t OFF_WT   = 37748736;
    const size_t OFF_ABF  = 80216064;
    const size_t OFF_H7   = 80216064;
    // early smalls (inside h6bf region):
    const size_t OFF_X32  = 0;
    const size_t OFF_KEY  = 5120000;
    const size_t OFF_CNT  = 5210112;
    const size_t OFF_SORT = 5300224;
    const size_t OFF_BOXD = 5308416;
    // late smalls (WtBuf tail, free during/after GEMM2):
    const size_t OFF_LOGIT = OFF_WT + 37748736;          // 2048*128*4 = 1,048,576
    const size_t OFF_W8T   = OFF_LOGIT + 1048576;        // 128*4096*2 = 1,048,576
    const size_t OFF_B8    = OFF_W8T + 1048576;          // 512
    const size_t OFF_SCD   = OFF_B8 + 512;               // 327,680
    const size_t OFF_CMAX  = OFF_SCD + 327680;           // 512
    const size_t OFF_CSUM  = OFF_CMAX + 512;             // 512

    float*    x32    = (float*)(ws + OFF_X32);
    float*    key    = (float*)(ws + OFF_KEY);
    int*      cnt    = (int*)(ws + OFF_CNT);
    int*      sorted = (int*)(ws + OFF_SORT);
    double*   boxd   = (double*)(ws + OFF_BOXD);
    ushort_t* Abf    = (ushort_t*)(ws + OFF_ABF);
    ushort_t* Wt     = (ushort_t*)(ws + OFF_WT);
    ushort_t* h6bf   = (ushort_t*)(ws + OFF_H6);
    ushort_t* h7bf   = (ushort_t*)(ws + OFF_H7);
    float*    logits = (float*)(ws + OFF_LOGIT);
    ushort_t* Wt8    = (ushort_t*)(ws + OFF_W8T);
    float*    b8     = (float*)(ws + OFF_B8);
    double*   scd    = (double*)(ws + OFF_SCD);
    double*   cmax   = (double*)(ws + OFF_CMAX);
    double*   csum   = (double*)(ws + OFF_CSUM);

    float* outScores = out + NCL;
    float* outBoxes  = out + NCL + KTOP * NCL;

    // 1-4: bit-exact RPN path (unchanged)
    conv_chain_kernel<<<dim3(625, 2), 256, 0, stream>>>(features, rpn_w, rpn_b, x32);
    obj_chain_kernel<<<dim3(88), 256, 0, stream>>>(x32, cls_w, cls_b, key);
    hipMemsetAsync(cnt, 0, NOBJ * sizeof(int), stream);
    topk_count_kernel<<<dim3(88, 11), 256, 0, stream>>>(key, cnt);
    topk_scatter_kernel<<<dim3(88), 256, 0, stream>>>(cnt, sorted);
    boxes_kernel<<<dim3(8), 256, 0, stream>>>(sorted, x32, reg_w, reg_b, boxd, outBoxes);

    // 5: ROI align -> Abf (bf16)
    roi_kernel<<<dim3(KTOP), 256, 0, stream>>>(features, boxd, Abf);

    // 6: fc6 = Abf[2048,4608] x fc6_w[4608,9216] (+relu) -> h6bf, two N-halves
    transpose_cvt_kernel<<<dim3(72, 72), 256, 0, stream>>>(fc6_w, Wt, 4608, 9216, 0);
    gemm_bt_kernel<true, true><<<dim3(36, 16), 256, 0, stream>>>(Abf, Wt, fc6_b + 0,
                                                                 (void*)(h6bf + 0), 9216, 4608);
    transpose_cvt_kernel<<<dim3(72, 72), 256, 0, stream>>>(fc6_w, Wt, 4608, 9216, 4608);
    gemm_bt_kernel<true, true><<<dim3(36, 16), 256, 0, stream>>>(Abf, Wt, fc6_b + 4608,
                                                                 (void*)(h6bf + 4608), 9216, 4608);

    // 7: fc7 = h6bf[2048,9216] x fc7_w[9216,4096] (+relu) -> h7bf, two halves
    transpose_cvt_kernel<<<dim3(144, 32), 256, 0, stream>>>(fc7_w, Wt, 9216, 4096, 0);
    gemm_bt_kernel<true, true><<<dim3(16, 16), 256, 0, stream>>>(h6bf, Wt, fc7_b + 0,
                                                                 (void*)(h7bf + 0), 4096, 9216);
    transpose_cvt_kernel<<<dim3(144, 32), 256, 0, stream>>>(fc7_w, Wt, 9216, 4096, 2048);
    gemm_bt_kernel<true, true><<<dim3(16, 16), 256, 0, stream>>>(h6bf, Wt, fc7_b + 2048,
                                                                 (void*)(h7bf + 2048), 4096, 9216);

    // 8: fc8 both streams as one MFMA GEMM: h7bf[2048,4096] x Wt8^T -> logits[2048,128]
    pack_w8_kernel<<<dim3(2048), 256, 0, stream>>>(fc8c_w, fc8d_w, Wt8);
    pack_b8_kernel<<<dim3(1), 128, 0, stream>>>(fc8c_b, fc8d_b, b8);
    gemm_bt_kernel<false, false><<<dim3(1, 16), 256, 0, stream>>>(h7bf, Wt8, b8,
                                                                  (void*)logits, 128, 4096);

    // 9: softmaxes + scores + clipped colsum
    colstats_kernel<<<dim3(NCL), 256, 0, stream>>>(logits, cmax, csum);
    scores_kernel<<<dim3(8), 256, 0, stream>>>(logits, cmax, csum, scd, outScores);
    colsum_kernel<<<dim3(NCL), 256, 0, stream>>>(scd, out);
}